// Round 1
// baseline (218.363 us; speedup 1.0000x reference)
//
#include <hip/hip_runtime.h>

typedef short short8 __attribute__((ext_vector_type(8)));
typedef float floatx4 __attribute__((ext_vector_type(4)));

__device__ __forceinline__ short f2bf(float f) {
    union { float f; unsigned u; } v; v.f = f;
    unsigned r = v.u + 0x7fffu + ((v.u >> 16) & 1u);  // round-to-nearest-even
    return (short)(r >> 16);
}

// Convert lora_A (4096x64) and lora_B (64x4096) fp32 -> bf16 in MFMA B-operand
// fragment layout for mfma_f32_16x16x32_bf16:
//   B-operand: lane l holds B[k][col] with col = l&15, k = 8*(l>>4) + j, j=0..7
// Abf[((ks*4 + nt)*64 + lane)*8 + j] = A[(ks*32 + 8*(l>>4)+j)*64 + nt*16 + (l&15)]
// Bbf[((ct*2 + ks)*64 + lane)*8 + j] = B[(ks*32 + 8*(l>>4)+j)*4096 + ct*16 + (l&15)]
__global__ __launch_bounds__(256) void conv_ab(
    const float* __restrict__ A, const float* __restrict__ B,
    short* __restrict__ Abf, short* __restrict__ Bbf) {
    int i = blockIdx.x * 256 + threadIdx.x;   // 0 .. 262143
    int j    = i & 7;
    int lane = (i >> 3) & 63;
    int hi   = i >> 9;                        // A: ks*4+nt ; B: ct*2+ks
    int krow = 8 * (lane >> 4) + j;
    int cc   = lane & 15;
    {   // A fragments
        int ks = hi >> 2, nt = hi & 3;
        int k = ks * 32 + krow;
        int c = nt * 16 + cc;
        Abf[i] = f2bf(A[(size_t)k * 64 + c]);
    }
    {   // B fragments
        int ct = hi >> 1, ks = hi & 1;
        int k = ks * 32 + krow;
        int c = ct * 16 + cc;
        Bbf[i] = f2bf(B[(size_t)k * 4096 + c]);
    }
}

// k1: t[16384][64] (bf16) = x (fp32, cast to bf16) @ A
// grid: 1024 blocks (16 rows each), 4 waves/block, wave w -> n-tile w (16 cols)
__global__ __launch_bounds__(256) void k1_xA(
    const float* __restrict__ x, const float* __restrict__ tw,
    const short* __restrict__ Abf, short* __restrict__ t) {
    const int lane = threadIdx.x & 63;
    const int wave = threadIdx.x >> 6;
    const int rowbase = blockIdx.x * 16;
    const int rrow = lane & 15;
    const int row  = rowbase + rrow;
    const int kofs = (lane >> 4) * 8;
    const bool active = (tw[row] != 0.0f);
    const float* xp = x + (size_t)row * 4096 + kofs;
    const short8* bp0 = (const short8*)Abf;

    floatx4 acc = {0.f, 0.f, 0.f, 0.f};
    #pragma unroll 4
    for (int ks = 0; ks < 128; ++ks) {
        short8 xa = (short8)0;
        if (active) {
            floatx4 x0 = *(const floatx4*)(xp + ks * 32);
            floatx4 x1 = *(const floatx4*)(xp + ks * 32 + 4);
            xa[0] = f2bf(x0[0]); xa[1] = f2bf(x0[1]);
            xa[2] = f2bf(x0[2]); xa[3] = f2bf(x0[3]);
            xa[4] = f2bf(x1[0]); xa[5] = f2bf(x1[1]);
            xa[6] = f2bf(x1[2]); xa[7] = f2bf(x1[3]);
        }
        short8 bb = bp0[ks * 256 + wave * 64 + lane];
        acc = __builtin_amdgcn_mfma_f32_16x16x32_bf16(xa, bb, acc, 0, 0, 0);
    }
    // D layout: col = lane&15, row = 4*(lane>>4) + b
    const int trow = rowbase + (lane >> 4) * 4;
    const int tcol = wave * 16 + rrow;
    #pragma unroll
    for (int b = 0; b < 4; ++b)
        t[(size_t)(trow + b) * 64 + tcol] = f2bf(acc[b]);
}

// k2: out[16384][4096] (fp32) = (t @ B) * tw * 2
// grid: (1024, 16); block 256 = 4 waves; wave covers 16 rows x 64 cols
__global__ __launch_bounds__(256) void k2_tB(
    const short* __restrict__ t, const float* __restrict__ tw,
    const short* __restrict__ Bbf, float* __restrict__ out) {
    const int lane = threadIdx.x & 63;
    const int wave = threadIdx.x >> 6;
    const int rowbase = blockIdx.x * 16;
    const int colbase = blockIdx.y * 256 + wave * 64;
    const int rrow = lane & 15;
    const int kofs = (lane >> 4) * 8;

    // A-operand fragments from t: row = lane&15, k = kofs + j (+32 for ks=1)
    const short8* tp = (const short8*)(t + (size_t)(rowbase + rrow) * 64 + kofs);
    short8 a0 = tp[0];
    short8 a1 = tp[4];   // +32 shorts

    const short8* bp0 = (const short8*)Bbf;
    floatx4 acc[4] = {{0,0,0,0},{0,0,0,0},{0,0,0,0},{0,0,0,0}};
    #pragma unroll
    for (int nt = 0; nt < 4; ++nt) {
        int ct = (colbase >> 4) + nt;
        short8 b0 = bp0[(ct * 2 + 0) * 64 + lane];
        short8 b1 = bp0[(ct * 2 + 1) * 64 + lane];
        acc[nt] = __builtin_amdgcn_mfma_f32_16x16x32_bf16(a0, b0, acc[nt], 0, 0, 0);
        acc[nt] = __builtin_amdgcn_mfma_f32_16x16x32_bf16(a1, b1, acc[nt], 0, 0, 0);
    }

    const int r0 = rowbase + (lane >> 4) * 4;
    float w[4];
    #pragma unroll
    for (int b = 0; b < 4; ++b) w[b] = tw[r0 + b] * 2.0f;

    #pragma unroll
    for (int nt = 0; nt < 4; ++nt) {
        size_t co = (size_t)colbase + nt * 16 + rrow;
        #pragma unroll
        for (int b = 0; b < 4; ++b)
            out[(size_t)(r0 + b) * 4096 + co] = acc[nt][b] * w[b];
    }
}

extern "C" void kernel_launch(void* const* d_in, const int* in_sizes, int n_in,
                              void* d_out, int out_size, void* d_ws, size_t ws_size,
                              hipStream_t stream) {
    const float* x  = (const float*)d_in[0];   // (8,2048,4096)
    const float* tw = (const float*)d_in[1];   // (8,2048)
    const float* A  = (const float*)d_in[2];   // (4096,64)
    const float* B  = (const float*)d_in[3];   // (64,4096)
    float* out = (float*)d_out;                // (8,2048,4096) fp32

    short* Abf = (short*)d_ws;                 // 262144 bf16 = 512 KB
    short* Bbf = Abf + 262144;                 // 512 KB
    short* t   = Bbf + 262144;                 // 16384*64 bf16 = 2 MB

    conv_ab<<<1024, 256, 0, stream>>>(A, B, Abf, Bbf);
    k1_xA<<<1024, 256, 0, stream>>>(x, tw, Abf, t);
    k2_tB<<<dim3(1024, 16), 256, 0, stream>>>(t, tw, Bbf, out);
}

// Round 2
// 151.182 us; speedup vs baseline: 1.4444x; 1.4444x over previous
//
#include <hip/hip_runtime.h>

typedef short short8 __attribute__((ext_vector_type(8)));
typedef float floatx4 __attribute__((ext_vector_type(4)));

__device__ __forceinline__ short f2bf(float f) {
    union { float f; unsigned u; } v; v.f = f;
    unsigned r = v.u + 0x7fffu + ((v.u >> 16) & 1u);  // round-to-nearest-even
    return (short)(r >> 16);
}

// Convert lora_A (4096x64) and lora_B (64x4096) fp32 -> bf16 in MFMA B-operand
// fragment layout for mfma_f32_16x16x32_bf16:
//   B-operand: lane l holds B[k][col] with col = l&15, k = 8*(l>>4) + j, j=0..7
// Abf[((ks*4 + nt)*64 + lane)*8 + j] = A[(ks*32 + 8*(l>>4)+j)*64 + nt*16 + (l&15)]
// Bbf[((ct*2 + ks)*64 + lane)*8 + j] = B[(ks*32 + 8*(l>>4)+j)*4096 + ct*16 + (l&15)]
__global__ __launch_bounds__(256) void conv_ab(
    const float* __restrict__ A, const float* __restrict__ B,
    short* __restrict__ Abf, short* __restrict__ Bbf) {
    int i = blockIdx.x * 256 + threadIdx.x;   // 0 .. 262143
    int j    = i & 7;
    int lane = (i >> 3) & 63;
    int hi   = i >> 9;                        // A: ks*4+nt ; B: ct*2+ks
    int krow = 8 * (lane >> 4) + j;
    int cc   = lane & 15;
    {   // A fragments
        int ks = hi >> 2, nt = hi & 3;
        int k = ks * 32 + krow;
        int c = nt * 16 + cc;
        Abf[i] = f2bf(A[(size_t)k * 64 + c]);
    }
    {   // B fragments
        int ct = hi >> 1, ks = hi & 1;
        int k = ks * 32 + krow;
        int c = ct * 16 + cc;
        Bbf[i] = f2bf(B[(size_t)k * 4096 + c]);
    }
}

// k1: t2[p][16384][64] (bf16, p=0,1 K-partials) = partial sums of x @ A
// grid (1024, 2): blockIdx.x = 16-row group, blockIdx.y = K-half (2048)
// 4 waves; wave w owns K-slice of 512 (16 iters), computes ALL 4 n-tiles
// (4 independent MFMA chains), then cross-wave LDS reduce -> one bf16 partial.
__global__ __launch_bounds__(256) void k1_xA(
    const float* __restrict__ x, const float* __restrict__ tw,
    const short* __restrict__ Abf, short* __restrict__ t2) {
    __shared__ float red[4][16][65];
    const int lane = threadIdx.x & 63;
    const int wave = threadIdx.x >> 6;
    const int rowbase = blockIdx.x * 16;
    const int rrow = lane & 15;
    const int row  = rowbase + rrow;
    const int kofs = (lane >> 4) * 8;
    const int kbase = blockIdx.y * 2048 + wave * 512;
    const bool active = (tw[row] != 0.0f);
    const float* xp = x + (size_t)row * 4096 + kbase + kofs;
    // Abf fragment for global k-step ksg, n-tile nt: Abf8[(ksg*4 + nt)*64 + lane]
    const short8* bp = (const short8*)Abf + ((size_t)(kbase >> 5) * 4 * 64) + lane;

    floatx4 acc[4] = {{0,0,0,0},{0,0,0,0},{0,0,0,0},{0,0,0,0}};
    #pragma unroll 2
    for (int ks = 0; ks < 16; ++ks) {
        short8 xa = (short8)0;
        if (active) {
            floatx4 x0 = *(const floatx4*)(xp + ks * 32);
            floatx4 x1 = *(const floatx4*)(xp + ks * 32 + 4);
            xa[0] = f2bf(x0[0]); xa[1] = f2bf(x0[1]);
            xa[2] = f2bf(x0[2]); xa[3] = f2bf(x0[3]);
            xa[4] = f2bf(x1[0]); xa[5] = f2bf(x1[1]);
            xa[6] = f2bf(x1[2]); xa[7] = f2bf(x1[3]);
        }
        short8 b0 = bp[ks * 256 + 0 * 64];
        short8 b1 = bp[ks * 256 + 1 * 64];
        short8 b2 = bp[ks * 256 + 2 * 64];
        short8 b3 = bp[ks * 256 + 3 * 64];
        acc[0] = __builtin_amdgcn_mfma_f32_16x16x32_bf16(xa, b0, acc[0], 0, 0, 0);
        acc[1] = __builtin_amdgcn_mfma_f32_16x16x32_bf16(xa, b1, acc[1], 0, 0, 0);
        acc[2] = __builtin_amdgcn_mfma_f32_16x16x32_bf16(xa, b2, acc[2], 0, 0, 0);
        acc[3] = __builtin_amdgcn_mfma_f32_16x16x32_bf16(xa, b3, acc[3], 0, 0, 0);
    }

    // D layout: col = lane&15 (within n-tile), row = 4*(lane>>4) + b
    #pragma unroll
    for (int nt = 0; nt < 4; ++nt)
        #pragma unroll
        for (int b = 0; b < 4; ++b)
            red[wave][(lane >> 4) * 4 + b][nt * 16 + rrow] = acc[nt][b];
    __syncthreads();

    #pragma unroll
    for (int e = threadIdx.x; e < 1024; e += 256) {
        int r = e >> 6, c = e & 63;
        float s = red[0][r][c] + red[1][r][c] + red[2][r][c] + red[3][r][c];
        t2[((size_t)blockIdx.y * 16384 + rowbase + r) * 64 + c] = f2bf(s);
    }
}

// k2: out[16384][4096] (fp32) = ((t2[0] + t2[1]) @ B) * tw * 2
//   = t2[0]@B + t2[1]@B  -- feed both partials through MFMA reusing B frags.
// grid: (1024, 16); block 256 = 4 waves; wave covers 16 rows x 64 cols
__global__ __launch_bounds__(256) void k2_tB(
    const short* __restrict__ t2, const float* __restrict__ tw,
    const short* __restrict__ Bbf, float* __restrict__ out) {
    const int lane = threadIdx.x & 63;
    const int wave = threadIdx.x >> 6;
    const int rowbase = blockIdx.x * 16;
    const int colbase = blockIdx.y * 256 + wave * 64;
    const int rrow = lane & 15;
    const int kofs = (lane >> 4) * 8;

    // A-operand fragments from both t2 partials: row = lane&15, k = kofs + j
    const short8* t0p = (const short8*)(t2 + (size_t)(rowbase + rrow) * 64 + kofs);
    const short8* t1p = (const short8*)(t2 + (size_t)16384 * 64 + (size_t)(rowbase + rrow) * 64 + kofs);
    short8 a00 = t0p[0];
    short8 a01 = t0p[4];   // +32 shorts (k = 32..63)
    short8 a10 = t1p[0];
    short8 a11 = t1p[4];

    const short8* bp0 = (const short8*)Bbf;
    floatx4 acc[4] = {{0,0,0,0},{0,0,0,0},{0,0,0,0},{0,0,0,0}};
    #pragma unroll
    for (int nt = 0; nt < 4; ++nt) {
        int ct = (colbase >> 4) + nt;
        short8 b0 = bp0[(ct * 2 + 0) * 64 + lane];
        short8 b1 = bp0[(ct * 2 + 1) * 64 + lane];
        acc[nt] = __builtin_amdgcn_mfma_f32_16x16x32_bf16(a00, b0, acc[nt], 0, 0, 0);
        acc[nt] = __builtin_amdgcn_mfma_f32_16x16x32_bf16(a01, b1, acc[nt], 0, 0, 0);
        acc[nt] = __builtin_amdgcn_mfma_f32_16x16x32_bf16(a10, b0, acc[nt], 0, 0, 0);
        acc[nt] = __builtin_amdgcn_mfma_f32_16x16x32_bf16(a11, b1, acc[nt], 0, 0, 0);
    }

    const int r0 = rowbase + (lane >> 4) * 4;
    float w[4];
    #pragma unroll
    for (int b = 0; b < 4; ++b) w[b] = tw[r0 + b] * 2.0f;

    #pragma unroll
    for (int nt = 0; nt < 4; ++nt) {
        size_t co = (size_t)colbase + nt * 16 + rrow;
        #pragma unroll
        for (int b = 0; b < 4; ++b)
            out[(size_t)(r0 + b) * 4096 + co] = acc[nt][b] * w[b];
    }
}

extern "C" void kernel_launch(void* const* d_in, const int* in_sizes, int n_in,
                              void* d_out, int out_size, void* d_ws, size_t ws_size,
                              hipStream_t stream) {
    const float* x  = (const float*)d_in[0];   // (8,2048,4096)
    const float* tw = (const float*)d_in[1];   // (8,2048)
    const float* A  = (const float*)d_in[2];   // (4096,64)
    const float* B  = (const float*)d_in[3];   // (64,4096)
    float* out = (float*)d_out;                // (8,2048,4096) fp32

    short* Abf = (short*)d_ws;                 // 262144 bf16 = 512 KB
    short* Bbf = Abf + 262144;                 // 512 KB
    short* t2  = Bbf + 262144;                 // 2 x 16384 x 64 bf16 = 4 MB

    conv_ab<<<1024, 256, 0, stream>>>(A, B, Abf, Bbf);
    k1_xA<<<dim3(1024, 2), 256, 0, stream>>>(x, tw, Abf, t2);
    k2_tB<<<dim3(1024, 16), 256, 0, stream>>>(t2, tw, Bbf, out);
}

// Round 3
// 138.853 us; speedup vs baseline: 1.5726x; 1.0888x over previous
//
#include <hip/hip_runtime.h>

typedef short short8 __attribute__((ext_vector_type(8)));
typedef float floatx4 __attribute__((ext_vector_type(4)));

__device__ __forceinline__ short f2bf(float f) {
    union { float f; unsigned u; } v; v.f = f;
    unsigned r = v.u + 0x7fffu + ((v.u >> 16) & 1u);  // round-to-nearest-even
    return (short)(r >> 16);
}

// Convert lora_A (4096x64) and lora_B (64x4096) fp32 -> bf16 in MFMA B-operand
// fragment layout for mfma_f32_16x16x32_bf16:
//   B-operand: lane l holds B[k][col] with col = l&15, k = 8*(l>>4) + j, j=0..7
__global__ __launch_bounds__(256) void conv_ab(
    const float* __restrict__ A, const float* __restrict__ B,
    short* __restrict__ Abf, short* __restrict__ Bbf) {
    int i = blockIdx.x * 256 + threadIdx.x;   // 0 .. 262143
    int j    = i & 7;
    int lane = (i >> 3) & 63;
    int hi   = i >> 9;                        // A: ks*4+nt ; B: ct*2+ks
    int krow = 8 * (lane >> 4) + j;
    int cc   = lane & 15;
    {   // A fragments
        int ks = hi >> 2, nt = hi & 3;
        int k = ks * 32 + krow;
        int c = nt * 16 + cc;
        Abf[i] = f2bf(A[(size_t)k * 64 + c]);
    }
    {   // B fragments
        int ct = hi >> 1, ks = hi & 1;
        int k = ks * 32 + krow;
        int c = ct * 16 + cc;
        Bbf[i] = f2bf(B[(size_t)k * 4096 + c]);
    }
}

// Fused: per block of 16 rows,
//   phase 1: t[16][64] = x[rows]@A  (split-K over 4 waves, LDS f32 reduce -> bf16 LDS)
//   phase 2: out[rows][cols] = (t@B) * tw * 2  (wave w owns 1024 cols)
__global__ __launch_bounds__(256) void fused(
    const float* __restrict__ x, const float* __restrict__ tw,
    const short* __restrict__ Abf, const short* __restrict__ Bbf,
    float* __restrict__ out) {
    __shared__ float red[4][16][65];      // per-wave f32 partials
    __shared__ short tl[16][80];          // reduced t, bf16, padded to 160B rows

    const int lane = threadIdx.x & 63;
    const int wave = threadIdx.x >> 6;
    const int rowbase = blockIdx.x * 16;
    const int rrow = lane & 15;
    const int kgrp = lane >> 4;           // 0..3
    const int kofs = kgrp * 8;

    // ---------------- phase 1: t = x @ A, split-K 1024 per wave ----------------
    {
        const int row = rowbase + rrow;
        const bool active = (tw[row] != 0.0f);
        const float* xp = x + (size_t)row * 4096 + wave * 1024 + kofs;
        // Abf8[(ksg*4 + nt)*64 + lane], ksg = wave*32 + ks
        const short8* ap = (const short8*)Abf + (size_t)wave * 8192 + lane;

        floatx4 acc[4] = {{0,0,0,0},{0,0,0,0},{0,0,0,0},{0,0,0,0}};
        #pragma unroll 2
        for (int ks = 0; ks < 32; ++ks) {
            short8 xa = (short8)0;
            if (active) {
                floatx4 x0 = *(const floatx4*)(xp + ks * 32);
                floatx4 x1 = *(const floatx4*)(xp + ks * 32 + 4);
                xa[0] = f2bf(x0[0]); xa[1] = f2bf(x0[1]);
                xa[2] = f2bf(x0[2]); xa[3] = f2bf(x0[3]);
                xa[4] = f2bf(x1[0]); xa[5] = f2bf(x1[1]);
                xa[6] = f2bf(x1[2]); xa[7] = f2bf(x1[3]);
            }
            short8 b0 = ap[ks * 256 + 0 * 64];
            short8 b1 = ap[ks * 256 + 1 * 64];
            short8 b2 = ap[ks * 256 + 2 * 64];
            short8 b3 = ap[ks * 256 + 3 * 64];
            acc[0] = __builtin_amdgcn_mfma_f32_16x16x32_bf16(xa, b0, acc[0], 0, 0, 0);
            acc[1] = __builtin_amdgcn_mfma_f32_16x16x32_bf16(xa, b1, acc[1], 0, 0, 0);
            acc[2] = __builtin_amdgcn_mfma_f32_16x16x32_bf16(xa, b2, acc[2], 0, 0, 0);
            acc[3] = __builtin_amdgcn_mfma_f32_16x16x32_bf16(xa, b3, acc[3], 0, 0, 0);
        }
        // D layout: col = lane&15 (in n-tile), row = 4*kgrp + b
        #pragma unroll
        for (int nt = 0; nt < 4; ++nt)
            #pragma unroll
            for (int b = 0; b < 4; ++b)
                red[wave][kgrp * 4 + b][nt * 16 + rrow] = acc[nt][b];
    }
    __syncthreads();
    #pragma unroll
    for (int e = threadIdx.x; e < 1024; e += 256) {
        int r = e >> 6, c = e & 63;
        tl[r][c] = f2bf(red[0][r][c] + red[1][r][c] + red[2][r][c] + red[3][r][c]);
    }
    __syncthreads();

    // ---------------- phase 2: out = (t @ B) * tw * 2 ----------------
    // A-operand: lane holds t[rrow][k], k = kofs+j (a0), 32+kofs+j (a1)
    short8 a0 = *(const short8*)&tl[rrow][kofs];
    short8 a1 = *(const short8*)&tl[rrow][32 + kofs];

    float w[4];
    #pragma unroll
    for (int b = 0; b < 4; ++b) w[b] = tw[rowbase + kgrp * 4 + b] * 2.0f;

    const short8* bp0 = (const short8*)Bbf;
    const int r0 = rowbase + kgrp * 4;

    #pragma unroll 2
    for (int tt = 0; tt < 16; ++tt) {
        const int colbase = wave * 1024 + tt * 64;
        const int ctb = colbase >> 4;
        floatx4 acc[4] = {{0,0,0,0},{0,0,0,0},{0,0,0,0},{0,0,0,0}};
        #pragma unroll
        for (int nt = 0; nt < 4; ++nt) {
            short8 b0 = bp0[((ctb + nt) * 2 + 0) * 64 + lane];
            short8 b1 = bp0[((ctb + nt) * 2 + 1) * 64 + lane];
            acc[nt] = __builtin_amdgcn_mfma_f32_16x16x32_bf16(a0, b0, acc[nt], 0, 0, 0);
            acc[nt] = __builtin_amdgcn_mfma_f32_16x16x32_bf16(a1, b1, acc[nt], 0, 0, 0);
        }
        #pragma unroll
        for (int nt = 0; nt < 4; ++nt) {
            size_t co = (size_t)colbase + nt * 16 + rrow;
            #pragma unroll
            for (int b = 0; b < 4; ++b)
                out[(size_t)(r0 + b) * 4096 + co] = acc[nt][b] * w[b];
        }
    }
}

extern "C" void kernel_launch(void* const* d_in, const int* in_sizes, int n_in,
                              void* d_out, int out_size, void* d_ws, size_t ws_size,
                              hipStream_t stream) {
    const float* x  = (const float*)d_in[0];   // (8,2048,4096)
    const float* tw = (const float*)d_in[1];   // (8,2048)
    const float* A  = (const float*)d_in[2];   // (4096,64)
    const float* B  = (const float*)d_in[3];   // (64,4096)
    float* out = (float*)d_out;                // (8,2048,4096) fp32

    short* Abf = (short*)d_ws;                 // 262144 bf16 = 512 KB
    short* Bbf = Abf + 262144;                 // 512 KB

    conv_ab<<<1024, 256, 0, stream>>>(A, B, Abf, Bbf);
    fused<<<1024, 256, 0, stream>>>(x, tw, Abf, Bbf, out);
}